// Round 1
// baseline (1419.484 us; speedup 1.0000x reference)
//
#include <hip/hip_runtime.h>
#include <hip/hip_bf16.h>

#define N_NODES 500000
#define FEAT 256
#define NCLS 128
#define NSEG 2048

typedef __attribute__((ext_vector_type(8))) short bfrag8;   // 8 bf16 = 4 VGPRs
typedef __attribute__((ext_vector_type(4))) float facc4;    // 4 fp32 acc

__device__ __forceinline__ unsigned short f2bf(float f) {
    unsigned int u = __float_as_uint(f);
    u += 0x7FFFu + ((u >> 16) & 1u);   // round-to-nearest-even
    return (unsigned short)(u >> 16);
}

// K0: transpose + bf16-convert weights. W1t[f][d] = W1[d][f], W2t[c][d] = W2[d][c]
__global__ void prep_kernel(const float* __restrict__ W1, const float* __restrict__ W2,
                            short* __restrict__ W1t, short* __restrict__ W2t) {
    int idx = blockIdx.x * 256 + threadIdx.x;
    if (idx < FEAT * FEAT) {
        int d = idx >> 8, f = idx & 255;
        W1t[f * FEAT + d] = (short)f2bf(W1[idx]);
    }
    if (idx < FEAT * NCLS) {
        int d = idx >> 7, c = idx & 127;
        W2t[c * FEAT + d] = (short)f2bf(W2[idx]);
    }
}

// K1: fused MLP. Block = 256 threads (4 waves), 128 rows/block.
// LDS tile 128x256 bf16 (64 KB), XOR-swizzled in 16B groups: element (r,c) lives
// at r*256 + ((c>>3) ^ (r&7))*8 + (c&7). Breaks the 512B-row-stride bank conflict
// on A-fragment ds_read_b128 (16-way -> 2-way=free) while keeping 16B alignment.
__global__ __launch_bounds__(256, 2)
void mlp_kernel(const float* __restrict__ H, const short* __restrict__ W1t,
                const float* __restrict__ b1, const short* __restrict__ W2t,
                const float* __restrict__ b2, float* __restrict__ logits) {
    __shared__ short tile[128 * 256];

    const int tid  = threadIdx.x;
    const int lane = tid & 63;
    const int l15  = lane & 15;
    const int quad = lane >> 4;
    const int wave = tid >> 6;
    const int row0 = blockIdx.x * 128;

    // ---- stage H tile (fp32 -> bf16) ----
    #pragma unroll
    for (int it = 0; it < 32; ++it) {
        int flat = it * 1024 + tid * 4;      // 4 rows per iteration
        int r = flat >> 8, c = flat & 255;
        float4 v = {0.f, 0.f, 0.f, 0.f};
        if (row0 + r < N_NODES)
            v = *reinterpret_cast<const float4*>(H + (size_t)(row0 + r) * FEAT + c);
        short4 s;
        s.x = (short)f2bf(v.x); s.y = (short)f2bf(v.y);
        s.z = (short)f2bf(v.z); s.w = (short)f2bf(v.w);
        int g = (c >> 3) ^ (r & 7);
        *reinterpret_cast<short4*>(&tile[r * 256 + g * 8 + (c & 7)]) = s;
    }
    __syncthreads();

    // wave handles rows [wave*32, wave*32+32)
    const int r0 = wave * 32 + l15;
    const int r1 = wave * 32 + 16 + l15;
    const int rx = l15 & 7;                  // (r0&7) == (r1&7) == l15&7

    // ---- GEMM1: h = relu(Hs @ W1 + b1), 32 rows x 256 cols per wave ----
    facc4 acc[2][16];
    #pragma unroll
    for (int rt = 0; rt < 2; ++rt)
        #pragma unroll
        for (int ct = 0; ct < 16; ++ct)
            acc[rt][ct] = (facc4){0.f, 0.f, 0.f, 0.f};

    #pragma unroll
    for (int kk = 0; kk < 8; ++kk) {
        int kb = kk * 32 + quad * 8;         // lane's K base (A/B frag: k=quad*8..+8)
        int gs = ((kb >> 3) ^ rx) << 3;      // swizzled group offset
        bfrag8 a0 = *reinterpret_cast<const bfrag8*>(&tile[r0 * 256 + gs]);
        bfrag8 a1 = *reinterpret_cast<const bfrag8*>(&tile[r1 * 256 + gs]);
        #pragma unroll
        for (int ct = 0; ct < 16; ++ct) {
            bfrag8 b = *reinterpret_cast<const bfrag8*>(&W1t[(ct * 16 + l15) * FEAT + kb]);
            acc[0][ct] = __builtin_amdgcn_mfma_f32_16x16x32_bf16(a0, b, acc[0][ct], 0, 0, 0);
            acc[1][ct] = __builtin_amdgcn_mfma_f32_16x16x32_bf16(a1, b, acc[1][ct], 0, 0, 0);
        }
    }

    // ---- epilogue1: bias + relu, write h (bf16) back into same LDS rows ----
    // C/D layout: col = l15 (+16*ct), row = quad*4 + i (+16*rt). Wave owns its rows,
    // so no barrier needed: in-wave data deps order LDS read->write.
    #pragma unroll
    for (int ct = 0; ct < 16; ++ct) {
        float bias = b1[ct * 16 + l15];
        int c = ct * 16 + l15;
        #pragma unroll
        for (int rt = 0; rt < 2; ++rt) {
            int rbase = wave * 32 + rt * 16 + quad * 4;
            #pragma unroll
            for (int i = 0; i < 4; ++i) {
                float v = fmaxf(acc[rt][ct][i] + bias, 0.f);
                int r = rbase + i;
                int g = (c >> 3) ^ (r & 7);
                tile[r * 256 + g * 8 + (c & 7)] = (short)f2bf(v);
            }
        }
    }

    // ---- GEMM2: logits = h @ W2 + b2, 32 rows x 128 cols per wave ----
    facc4 acc2[2][8];
    #pragma unroll
    for (int rt = 0; rt < 2; ++rt)
        #pragma unroll
        for (int ct = 0; ct < 8; ++ct)
            acc2[rt][ct] = (facc4){0.f, 0.f, 0.f, 0.f};

    #pragma unroll
    for (int kk = 0; kk < 8; ++kk) {
        int kb = kk * 32 + quad * 8;
        int gs = ((kb >> 3) ^ rx) << 3;
        bfrag8 a0 = *reinterpret_cast<const bfrag8*>(&tile[r0 * 256 + gs]);
        bfrag8 a1 = *reinterpret_cast<const bfrag8*>(&tile[r1 * 256 + gs]);
        #pragma unroll
        for (int ct = 0; ct < 8; ++ct) {
            bfrag8 b = *reinterpret_cast<const bfrag8*>(&W2t[(ct * 16 + l15) * FEAT + kb]);
            acc2[0][ct] = __builtin_amdgcn_mfma_f32_16x16x32_bf16(a0, b, acc2[0][ct], 0, 0, 0);
            acc2[1][ct] = __builtin_amdgcn_mfma_f32_16x16x32_bf16(a1, b, acc2[1][ct], 0, 0, 0);
        }
    }

    // ---- epilogue2: bias + store logits (fp32) ----
    #pragma unroll
    for (int ct = 0; ct < 8; ++ct) {
        float bias = b2[ct * 16 + l15];
        int c = ct * 16 + l15;
        #pragma unroll
        for (int rt = 0; rt < 2; ++rt) {
            int rbase = row0 + wave * 32 + rt * 16 + quad * 4;
            #pragma unroll
            for (int i = 0; i < 4; ++i) {
                int r = rbase + i;
                if (r < N_NODES)
                    logits[(size_t)r * NCLS + c] = acc2[rt][ct][i] + bias;
            }
        }
    }
}

// K2: per-segment sum of exp(logits). One block per segment; batch is sorted,
// bounds via binary search. Deterministic (no atomics).
__global__ void seg_sum_kernel(const float* __restrict__ logits,
                               const int* __restrict__ batch,
                               float* __restrict__ Lsum) {
    int seg = blockIdx.x;
    int lo = 0, hi = N_NODES;
    while (lo < hi) { int m = (lo + hi) >> 1; if (batch[m] < seg) lo = m + 1; else hi = m; }
    int start = lo;
    hi = N_NODES;
    while (lo < hi) { int m = (lo + hi) >> 1; if (batch[m] < seg + 1) lo = m + 1; else hi = m; }
    int end = lo;

    int t = threadIdx.x;
    int c = t & 127, half = t >> 7;
    float s = 0.f;
    for (int r = start + half; r < end; r += 2)
        s += __expf(logits[(size_t)r * NCLS + c]);

    __shared__ float red[256];
    red[t] = s;
    __syncthreads();
    if (half == 0) Lsum[seg * NCLS + c] = red[c] + red[c + 128];
}

// K3: probs = exp(logit) / Lsum[seg][c]  (== exp(x-max)/sum(exp(x-max)))
__global__ void probs_kernel(const float* __restrict__ logits,
                             const int* __restrict__ batch,
                             const float* __restrict__ Lsum,
                             float* __restrict__ probs) {
    int idx = blockIdx.x * 256 + threadIdx.x;
    int n = idx >> 5;
    if (n >= N_NODES) return;
    int c4 = (idx & 31) << 2;
    int seg = batch[n];
    float4 lg = *reinterpret_cast<const float4*>(&logits[(size_t)n * NCLS + c4]);
    float4 L  = *reinterpret_cast<const float4*>(&Lsum[(size_t)seg * NCLS + c4]);
    float4 p;
    p.x = __expf(lg.x) / L.x; p.y = __expf(lg.y) / L.y;
    p.z = __expf(lg.z) / L.z; p.w = __expf(lg.w) / L.w;
    *reinterpret_cast<float4*>(&probs[(size_t)n * NCLS + c4]) = p;
}

extern "C" void kernel_launch(void* const* d_in, const int* in_sizes, int n_in,
                              void* d_out, int out_size, void* d_ws, size_t ws_size,
                              hipStream_t stream) {
    const float* H     = (const float*)d_in[0];
    const int*   batch = (const int*)d_in[1];
    // d_in[2] = num_segments (scalar) — constant 2048, unused
    const float* W1    = (const float*)d_in[3];
    const float* b1    = (const float*)d_in[4];
    const float* W2    = (const float*)d_in[5];
    const float* b2    = (const float*)d_in[6];

    float* out    = (float*)d_out;
    float* logits = out;                                   // [N, 128]
    float* probs  = out + (size_t)N_NODES * NCLS;          // [N, 128]

    char* ws = (char*)d_ws;
    short* W1t  = (short*)ws;                              // 256*256 bf16 = 128 KB
    short* W2t  = (short*)(ws + 131072);                   // 128*256 bf16 = 64 KB
    float* Lsum = (float*)(ws + 131072 + 65536);           // 2048*128 fp32 = 1 MB

    prep_kernel<<<256, 256, 0, stream>>>(W1, W2, W1t, W2t);
    mlp_kernel<<<(N_NODES + 127) / 128, 256, 0, stream>>>(H, W1t, b1, W2t, b2, logits);
    seg_sum_kernel<<<NSEG, 256, 0, stream>>>(logits, batch, Lsum);
    probs_kernel<<<(N_NODES * 32 + 255) / 256, 256, 0, stream>>>(logits, batch, Lsum, probs);
}

// Round 2
// 1308.408 us; speedup vs baseline: 1.0849x; 1.0849x over previous
//
#include <hip/hip_runtime.h>
#include <hip/hip_bf16.h>

#define N_NODES 500000
#define FEAT 256
#define NCLS 128
#define NSEG 2048

typedef __attribute__((ext_vector_type(8))) short bfrag8;   // 8 bf16 = 4 VGPRs
typedef __attribute__((ext_vector_type(4))) float facc4;    // 4 fp32 acc

__device__ __forceinline__ unsigned short f2bf(float f) {
    unsigned int u = __float_as_uint(f);
    u += 0x7FFFu + ((u >> 16) & 1u);   // round-to-nearest-even
    return (unsigned short)(u >> 16);
}

// K0: transpose + bf16-convert weights. W1t[f][d] = W1[d][f], W2t[c][d] = W2[d][c]
__global__ void prep_kernel(const float* __restrict__ W1, const float* __restrict__ W2,
                            short* __restrict__ W1t, short* __restrict__ W2t) {
    int idx = blockIdx.x * 256 + threadIdx.x;
    if (idx < FEAT * FEAT) {
        int d = idx >> 8, f = idx & 255;
        W1t[f * FEAT + d] = (short)f2bf(W1[idx]);
    }
    if (idx < FEAT * NCLS) {
        int d = idx >> 7, c = idx & 127;
        W2t[c * FEAT + d] = (short)f2bf(W2[idx]);
    }
}

// K1: fused MLP, barrier-free. 4 waves/block, each wave owns 32 rows.
// A loaded directly from global fp32 (2x dwordx4 per strip per kk), cvt in regs.
// LDS only for per-wave h transpose (C/D layout -> A layout), 16 KB/wave,
// no __syncthreads anywhere (in-wave lgkmcnt ordering suffices).
__global__ __launch_bounds__(256, 2)
void mlp_kernel(const float* __restrict__ H, const short* __restrict__ W1t,
                const float* __restrict__ b1, const short* __restrict__ W2t,
                const float* __restrict__ b2, float* __restrict__ logits) {
    __shared__ short hb[4][32 * 256];   // per-wave h buffer, XOR-swizzled 8-elem groups

    const int tid  = threadIdx.x;
    const int lane = tid & 63;
    const int l15  = lane & 15;
    const int quad = lane >> 4;
    const int wave = tid >> 6;
    const int row0 = blockIdx.x * 128 + wave * 32;
    short* hw = hb[wave];

    // clamped row pointers (OOB rows compute garbage, never stored)
    const int rg0 = min(row0 + l15,      N_NODES - 1);
    const int rg1 = min(row0 + 16 + l15, N_NODES - 1);
    const float* rA0 = H + (size_t)rg0 * FEAT;
    const float* rA1 = H + (size_t)rg1 * FEAT;

    // ---- GEMM1: h = relu(A @ W1 + b1); acc 32 rows x 256 cols per wave ----
    facc4 acc[2][16];
    #pragma unroll
    for (int rt = 0; rt < 2; ++rt)
        #pragma unroll
        for (int ct = 0; ct < 16; ++ct)
            acc[rt][ct] = (facc4){0.f, 0.f, 0.f, 0.f};

    #pragma unroll
    for (int kk = 0; kk < 8; ++kk) {
        const int kb = kk * 32 + quad * 8;          // lane's K base (8 elems)
        float4 lo0 = *reinterpret_cast<const float4*>(rA0 + kb);
        float4 hi0 = *reinterpret_cast<const float4*>(rA0 + kb + 4);
        float4 lo1 = *reinterpret_cast<const float4*>(rA1 + kb);
        float4 hi1 = *reinterpret_cast<const float4*>(rA1 + kb + 4);
        bfrag8 a0, a1;
        a0[0]=(short)f2bf(lo0.x); a0[1]=(short)f2bf(lo0.y); a0[2]=(short)f2bf(lo0.z); a0[3]=(short)f2bf(lo0.w);
        a0[4]=(short)f2bf(hi0.x); a0[5]=(short)f2bf(hi0.y); a0[6]=(short)f2bf(hi0.z); a0[7]=(short)f2bf(hi0.w);
        a1[0]=(short)f2bf(lo1.x); a1[1]=(short)f2bf(lo1.y); a1[2]=(short)f2bf(lo1.z); a1[3]=(short)f2bf(lo1.w);
        a1[4]=(short)f2bf(hi1.x); a1[5]=(short)f2bf(hi1.y); a1[6]=(short)f2bf(hi1.z); a1[7]=(short)f2bf(hi1.w);
        #pragma unroll
        for (int ct = 0; ct < 16; ++ct) {
            bfrag8 b = *reinterpret_cast<const bfrag8*>(&W1t[(ct * 16 + l15) * FEAT + kb]);
            acc[0][ct] = __builtin_amdgcn_mfma_f32_16x16x32_bf16(a0, b, acc[0][ct], 0, 0, 0);
            acc[1][ct] = __builtin_amdgcn_mfma_f32_16x16x32_bf16(a1, b, acc[1][ct], 0, 0, 0);
        }
    }

    // ---- epilogue1: bias + relu -> per-wave LDS (swizzled), scalar b16 writes ----
    // C/D layout: col = ct*16 + l15, local row = rt*16 + quad*4 + i
    #pragma unroll
    for (int ct = 0; ct < 16; ++ct) {
        float bias = b1[ct * 16 + l15];
        int c = ct * 16 + l15;
        #pragma unroll
        for (int rt = 0; rt < 2; ++rt) {
            int rbase = rt * 16 + quad * 4;
            #pragma unroll
            for (int i = 0; i < 4; ++i) {
                float v = fmaxf(acc[rt][ct][i] + bias, 0.f);
                int r = rbase + i;
                int g = (c >> 3) ^ (r & 7);
                hw[r * 256 + g * 8 + (c & 7)] = (short)f2bf(v);
            }
        }
    }

    // ---- GEMM2: logits = h @ W2 + b2 (A-frags from per-wave LDS) ----
    const int rx = l15 & 7;      // (l15 & 7) == ((16+l15) & 7)
    facc4 acc2[2][8];
    #pragma unroll
    for (int rt = 0; rt < 2; ++rt)
        #pragma unroll
        for (int ct = 0; ct < 8; ++ct)
            acc2[rt][ct] = (facc4){0.f, 0.f, 0.f, 0.f};

    #pragma unroll
    for (int kk = 0; kk < 8; ++kk) {
        const int kb = kk * 32 + quad * 8;
        const int gs = ((kb >> 3) ^ rx) << 3;
        bfrag8 a0 = *reinterpret_cast<const bfrag8*>(&hw[l15 * 256 + gs]);
        bfrag8 a1 = *reinterpret_cast<const bfrag8*>(&hw[(16 + l15) * 256 + gs]);
        #pragma unroll
        for (int ct = 0; ct < 8; ++ct) {
            bfrag8 b = *reinterpret_cast<const bfrag8*>(&W2t[(ct * 16 + l15) * FEAT + kb]);
            acc2[0][ct] = __builtin_amdgcn_mfma_f32_16x16x32_bf16(a0, b, acc2[0][ct], 0, 0, 0);
            acc2[1][ct] = __builtin_amdgcn_mfma_f32_16x16x32_bf16(a1, b, acc2[1][ct], 0, 0, 0);
        }
    }

    // ---- epilogue2: bias + store logits (fp32, guarded) ----
    #pragma unroll
    for (int ct = 0; ct < 8; ++ct) {
        float bias = b2[ct * 16 + l15];
        int c = ct * 16 + l15;
        #pragma unroll
        for (int rt = 0; rt < 2; ++rt) {
            int rbase = row0 + rt * 16 + quad * 4;
            #pragma unroll
            for (int i = 0; i < 4; ++i) {
                int r = rbase + i;
                if (r < N_NODES)
                    logits[(size_t)r * NCLS + c] = acc2[rt][ct][i] + bias;
            }
        }
    }
}

// K2: per-segment sum of exp(logits). One block per segment, float4 loads,
// 8 rows/iter, LDS tree reduce. Deterministic (no atomics).
__global__ void seg_sum_kernel(const float* __restrict__ logits,
                               const int* __restrict__ batch,
                               float* __restrict__ Lsum) {
    int seg = blockIdx.x;
    int lo = 0, hi = N_NODES;
    while (lo < hi) { int m = (lo + hi) >> 1; if (batch[m] < seg) lo = m + 1; else hi = m; }
    int start = lo;
    hi = N_NODES;
    while (lo < hi) { int m = (lo + hi) >> 1; if (batch[m] < seg + 1) lo = m + 1; else hi = m; }
    int end = lo;

    int t = threadIdx.x;
    int cg = t & 31;          // col group (4 cols)
    int rs = t >> 5;          // row slice 0..7
    float4 s = {0.f, 0.f, 0.f, 0.f};
    for (int r = start + rs; r < end; r += 8) {
        float4 v = *reinterpret_cast<const float4*>(&logits[(size_t)r * NCLS + cg * 4]);
        s.x += __expf(v.x); s.y += __expf(v.y);
        s.z += __expf(v.z); s.w += __expf(v.w);
    }

    __shared__ float4 red[8][32];
    red[rs][cg] = s;
    __syncthreads();
    if (t < 32) {
        float4 a = red[0][t];
        #pragma unroll
        for (int k = 1; k < 8; ++k) {
            float4 b = red[k][t];
            a.x += b.x; a.y += b.y; a.z += b.z; a.w += b.w;
        }
        *reinterpret_cast<float4*>(&Lsum[(size_t)seg * NCLS + t * 4]) = a;
    }
}

// K3: probs = exp(logit) / Lsum[seg][c]
__global__ void probs_kernel(const float* __restrict__ logits,
                             const int* __restrict__ batch,
                             const float* __restrict__ Lsum,
                             float* __restrict__ probs) {
    int idx = blockIdx.x * 256 + threadIdx.x;
    int n = idx >> 5;
    if (n >= N_NODES) return;
    int c4 = (idx & 31) << 2;
    int seg = batch[n];
    float4 lg = *reinterpret_cast<const float4*>(&logits[(size_t)n * NCLS + c4]);
    float4 L  = *reinterpret_cast<const float4*>(&Lsum[(size_t)seg * NCLS + c4]);
    float4 p;
    p.x = __expf(lg.x) / L.x; p.y = __expf(lg.y) / L.y;
    p.z = __expf(lg.z) / L.z; p.w = __expf(lg.w) / L.w;
    *reinterpret_cast<float4*>(&probs[(size_t)n * NCLS + c4]) = p;
}

extern "C" void kernel_launch(void* const* d_in, const int* in_sizes, int n_in,
                              void* d_out, int out_size, void* d_ws, size_t ws_size,
                              hipStream_t stream) {
    const float* H     = (const float*)d_in[0];
    const int*   batch = (const int*)d_in[1];
    // d_in[2] = num_segments (scalar) — constant 2048, unused
    const float* W1    = (const float*)d_in[3];
    const float* b1    = (const float*)d_in[4];
    const float* W2    = (const float*)d_in[5];
    const float* b2    = (const float*)d_in[6];

    float* out    = (float*)d_out;
    float* logits = out;                                   // [N, 128]
    float* probs  = out + (size_t)N_NODES * NCLS;          // [N, 128]

    char* ws = (char*)d_ws;
    short* W1t  = (short*)ws;                              // 256*256 bf16 = 128 KB
    short* W2t  = (short*)(ws + 131072);                   // 128*256 bf16 = 64 KB
    float* Lsum = (float*)(ws + 131072 + 65536);           // 2048*128 fp32 = 1 MB

    prep_kernel<<<256, 256, 0, stream>>>(W1, W2, W1t, W2t);
    mlp_kernel<<<(N_NODES + 127) / 128, 256, 0, stream>>>(H, W1t, b1, W2t, b2, logits);
    seg_sum_kernel<<<NSEG, 256, 0, stream>>>(logits, batch, Lsum);
    probs_kernel<<<(N_NODES * 32 + 255) / 256, 256, 0, stream>>>(logits, batch, Lsum, probs);
}